// Round 1
// baseline (117.953 us; speedup 1.0000x reference)
//
#include <hip/hip_runtime.h>
#include <hip/hip_bf16.h>
#include <math.h>

#define WAVE 64

__device__ __forceinline__ double wave_sum_d(double x) {
#pragma unroll
  for (int o = 32; o >= 1; o >>= 1) x += __shfl_xor(x, o, WAVE);
  return x;
}

__device__ __forceinline__ float wave_min_f(float x) {
#pragma unroll
  for (int o = 32; o >= 1; o >>= 1) x = fminf(x, __shfl_xor(x, o, WAVE));
  return x;
}

// ---------------- Kernel 1: per-row soft-hinge loss ----------------
// l[b] = 1                              if target is argmax (margin >= 0)
//      = relu(1 - z_y + logsumexp(z))   otherwise
__global__ void row_loss_kernel(const float* __restrict__ outp,
                                const int* __restrict__ target,
                                float* __restrict__ lv,
                                int B, int C) {
  const int lane = threadIdx.x & (WAVE - 1);
  const int wid  = threadIdx.x >> 6;
  const int row  = blockIdx.x * (blockDim.x >> 6) + wid;
  if (row >= B) return;

  const float* rp = outp + (size_t)row * (size_t)C;
  const int tgt = target[row];
  const float zy = rp[tgt];  // same addr across lanes -> broadcast load

  const int C4 = C >> 2;
  const float4* rp4 = (const float4*)rp;

  // pass 1: row max
  float m = -INFINITY;
  for (int i = lane; i < C4; i += WAVE) {
    float4 v = rp4[i];
    m = fmaxf(m, fmaxf(fmaxf(v.x, v.y), fmaxf(v.z, v.w)));
  }
  for (int i = (C4 << 2) + lane; i < C; i += WAVE) m = fmaxf(m, rp[i]);
#pragma unroll
  for (int o = 32; o >= 1; o >>= 1) m = fmaxf(m, __shfl_xor(m, o, WAVE));

  // pass 2: sum exp(z - max)  (row is L1/L2-hot from pass 1)
  float s = 0.f;
  for (int i = lane; i < C4; i += WAVE) {
    float4 v = rp4[i];
    s += expf(v.x - m) + expf(v.y - m) + expf(v.z - m) + expf(v.w - m);
  }
  for (int i = (C4 << 2) + lane; i < C; i += WAVE) s += expf(rp[i] - m);
#pragma unroll
  for (int o = 32; o >= 1; o >>= 1) s += __shfl_xor(s, o, WAVE);

  if (lane == 0) {
    float lse = m + logf(s);
    float e = expf(zy - m);                  // e >= 1  <=>  margin >= 0
    float l = (e >= 1.0f) ? 1.0f : fmaxf(0.0f, 1.0f - zy + lse);
    lv[row] = l;
  }
}

// ---------------- Kernel 2: prefix selection + final scalar ----------------
// Selection "cum[i] <= B - i" over sorted-ascending l is a PREFIX since
// cum[i]+i is strictly increasing (l >= 0). Binary-search the value cutoff
// over float bit patterns (monotone predicate), then handle partial ties.
#define K2T 1024
#define KPT 32

__device__ __forceinline__ void block_sum2(double a, double b,
                                           double* sh_a, double* sh_b,
                                           double* ra, double* rb) {
  const int lane = threadIdx.x & 63, wid = threadIdx.x >> 6;
  a = wave_sum_d(a); b = wave_sum_d(b);
  if (lane == 0) { sh_a[wid] = a; sh_b[wid] = b; }
  __syncthreads();
  if (wid == 0) {
    double x = (lane < 16) ? sh_a[lane] : 0.0;
    double y = (lane < 16) ? sh_b[lane] : 0.0;
    x = wave_sum_d(x); y = wave_sum_d(y);
    if (lane == 0) { sh_a[0] = x; sh_b[0] = y; }
  }
  __syncthreads();
  *ra = sh_a[0]; *rb = sh_b[0];
  __syncthreads();
}

__global__ __launch_bounds__(K2T)
void select_kernel(const float* __restrict__ lv, float* __restrict__ outp, int B) {
  const int tid = threadIdx.x;
  const int lane = tid & 63, wid = tid >> 6;
  __shared__ double sh_a[16], sh_b[16];
  __shared__ float sh_f[16];

  // load 32 values/thread into registers (float4, coalesced); pad with +inf
  float v[KPT];
#pragma unroll
  for (int i = 0; i < KPT / 4; i++) {
    int idx4 = tid + i * K2T;
    if (idx4 * 4 < B) {
      float4 t = ((const float4*)lv)[idx4];
      v[i * 4 + 0] = t.x; v[i * 4 + 1] = t.y;
      v[i * 4 + 2] = t.z; v[i * 4 + 3] = t.w;
    } else {
      v[i * 4 + 0] = v[i * 4 + 1] = v[i * 4 + 2] = v[i * 4 + 3] = INFINITY;
    }
  }

  // count(margin < 0) == count(l > 1) (snd branch always yields > 1)
  double cn = 0.0;
#pragma unroll
  for (int i = 0; i < KPT; i++)
    if (v[i] > 1.0f && v[i] < INFINITY) cn += 1.0;
  double count_neg, dummy;
  block_sum2(cn, 0.0, sh_a, sh_b, &count_neg, &dummy);

  const double Bd = (double)B;

  // binary search over float bit patterns for largest t with
  // sum(l<=t) + cnt(l<=t) - 1 <= B   (predicate monotone decreasing in t)
  unsigned lo = 0u, hi = 0x7F800000u;  // C(0)=true, C(inf)=false
  while (hi - lo > 1u) {
    unsigned mid = lo + (hi - lo) / 2u;
    float t = __uint_as_float(mid);
    double s = 0.0, c = 0.0;
#pragma unroll
    for (int i = 0; i < KPT; i++)
      if (v[i] <= t) { s += (double)v[i]; c += 1.0; }
    double S, Cn;
    block_sum2(s, c, sh_a, sh_b, &S, &Cn);
    bool ok = (S + Cn - 1.0 <= Bd);
    if (ok) lo = mid; else hi = mid;
  }

  // recompute S, k0 at t* = lo
  const float tstar = __uint_as_float(lo);
  double s = 0.0, c = 0.0;
#pragma unroll
  for (int i = 0; i < KPT; i++)
    if (v[i] <= tstar) { s += (double)v[i]; c += 1.0; }
  double S, k0;
  block_sum2(s, c, sh_a, sh_b, &S, &k0);

  // v_next = min over l > t*
  float mn = INFINITY;
#pragma unroll
  for (int i = 0; i < KPT; i++)
    if (v[i] > tstar) mn = fminf(mn, v[i]);
  mn = wave_min_f(mn);
  if (lane == 0) sh_f[wid] = mn;
  __syncthreads();
  if (tid == 0) {
    float vnext = INFINITY;
    for (int w = 0; w < 16; w++) vnext = fminf(vnext, sh_f[w]);
    // partial-tie inclusion: S + j*v + (k0 + j - 1) <= B
    double rem = Bd - S - k0 + 1.0;
    double j = floor(rem / ((double)vnext + 1.0));
    if (j < 0.0) j = 0.0;
    double loss1 = S + j * (double)vnext;
    double loss2 = Bd - (k0 + j) + count_neg;
    outp[0] = (float)fmax(loss1, loss2);
  }
}

extern "C" void kernel_launch(void* const* d_in, const int* in_sizes, int n_in,
                              void* d_out, int out_size, void* d_ws, size_t ws_size,
                              hipStream_t stream) {
  const float* outp  = (const float*)d_in[0];
  const int* target  = (const int*)d_in[1];
  const int B = in_sizes[1];
  const int C = in_sizes[0] / B;

  float* lv = (float*)d_ws;            // B floats = 128 KB scratch
  float* out = (float*)d_out;

  const int waves_per_block = 4;       // 256 threads, 1 row per wave
  dim3 grid((B + waves_per_block - 1) / waves_per_block);
  row_loss_kernel<<<grid, waves_per_block * WAVE, 0, stream>>>(outp, target, lv, B, C);
  select_kernel<<<1, K2T, 0, stream>>>(lv, out, B);
}